// Round 4
// baseline (348.946 us; speedup 1.0000x reference)
//
#include <hip/hip_runtime.h>
#include <hip/hip_bf16.h>

// Problem constants (from reference setup_inputs)
constexpr int BB = 2;
constexpr int L  = 24;
constexpr int C  = 32;
constexpr int H  = 128;
constexpr int W  = 256;
constexpr int HW = H * W;          // 32768
constexpr int R  = 32;

// y[b,l,c,h,w] = sum_{t=0..l} k[c,t] * x[b,l-t,c,h,w]   (Lf=48 >= 2L-1: FFT == linear causal conv)
// k[c,t] = sum_r gamma[c,r] * exp(-t*nu[c,r]) * cos(t*theta[c,r])
// nu = exp(p[0,c,r]), theta = exp(p[1,c,r]), gamma = sqrt(max(1-exp(-2nu),1e-12))
//
// Evidence trail:
//  R1 (all-bf16 reads)  -> NaN   : fp32 data read as bf16 (random exponent bytes -> inf).
//  R2 (all-fp32 reads, bf16-packed stores) -> absmax 104.25.
//  R3 (device dtype detect) -> absmax IDENTICAL to R2 => detector resolved fp32/fp32,
//      so inputs are genuinely fp32 and the remaining error source is the OUTPUT dtype:
//      reference returns float32 ("else float*" per harness doc). Store fp32.

__global__ __launch_bounds__(256) void convlru_kernel(
    const void* __restrict__ xraw,
    const void* __restrict__ praw,
    float* __restrict__ y)
{
    __shared__ float kk_lds[L];

    // ---------- on-device input dtype detection (wave-uniform, ~free) ----------
    const int lane = threadIdx.x & 63;
    const unsigned int wx = ((const unsigned int*)xraw)[lane];
    const unsigned int wp = ((const unsigned int*)praw)[lane];
    const unsigned int hbx = (wx >> 8) & 0xFFu;
    const unsigned int hbp = (wp >> 8) & 0xFFu;
    const bool hitx = (hbx >= 0x3Cu && hbx <= 0x40u) || (hbx >= 0xBCu && hbx <= 0xC0u); // N(0,1) bf16 exp byte
    const bool hitp = (hbp == 0xBFu) || (hbp == 0xC0u);                                 // nu_log in (-4.61,-1.5)
    const bool x_is_bf16 = __popcll(__ballot(hitx)) >= 32;
    const bool p_is_bf16 = __popcll(__ballot(hitp)) >= 32;

    const int plane = blockIdx.y;          // b*C + c
    const int c = plane & (C - 1);
    const int b = plane >> 5;              // C == 32

    // Flat ELEMENT index of (b, l=0, c, hw). l-plane stride: C*HW elements.
    const size_t ebase = ((size_t)b * L * C + (size_t)c) * HW
                       + (size_t)blockIdx.x * 512 + (size_t)threadIdx.x * 2;

    // ---------- load x column (2 hw elems x 24 l) ----------
    float x0[L], x1[L];
    if (x_is_bf16) {
        const unsigned short* xs = (const unsigned short*)xraw;
        #pragma unroll
        for (int l = 0; l < L; ++l) {
            unsigned int w = *(const unsigned int*)(xs + ebase + (size_t)l * C * HW);
            x0[l] = __uint_as_float(w << 16);
            x1[l] = __uint_as_float(w & 0xffff0000u);
        }
    } else {
        const float* xf = (const float*)xraw;
        #pragma unroll
        for (int l = 0; l < L; ++l) {
            float2 v = *(const float2*)(xf + ebase + (size_t)l * C * HW);
            x0[l] = v.x;
            x1[l] = v.y;
        }
    }

    // ---------- lanes 0..23 compute k[c][t] ----------
    if (threadIdx.x < L) {
        const float t = (float)threadIdx.x;
        float acc = 0.f;
        #pragma unroll 8
        for (int r = 0; r < R; ++r) {
            float p0, p1;
            if (p_is_bf16) {
                const __hip_bfloat16* pb = (const __hip_bfloat16*)praw;
                p0 = __bfloat162float(pb[c * R + r]);
                p1 = __bfloat162float(pb[C * R + c * R + r]);
            } else {
                const float* pf = (const float*)praw;
                p0 = pf[c * R + r];
                p1 = pf[C * R + c * R + r];
            }
            float nu    = expf(p0);
            float theta = expf(p1);
            float lam   = expf(-nu);
            float gamma = sqrtf(fmaxf(1.0f - lam * lam, 1e-12f));
            acc = fmaf(gamma * expf(-t * nu), cosf(t * theta), acc);
        }
        kk_lds[threadIdx.x] = acc;
    }
    __syncthreads();

    float kk[L];
    #pragma unroll
    for (int t = 0; t < L; ++t) kk[t] = kk_lds[t];

    // ---------- causal conv along L, fully unrolled; fp32 stores ----------
    #pragma unroll
    for (int l = 0; l < L; ++l) {
        float a0 = 0.f, a1 = 0.f;
        #pragma unroll
        for (int t = 0; t <= l; ++t) {
            a0 = fmaf(kk[t], x0[l - t], a0);
            a1 = fmaf(kk[t], x1[l - t], a1);
        }
        float2 o; o.x = a0; o.y = a1;
        *(float2*)(y + ebase + (size_t)l * C * HW) = o;
    }
}

extern "C" void kernel_launch(void* const* d_in, const int* in_sizes, int n_in,
                              void* d_out, int out_size, void* d_ws, size_t ws_size,
                              hipStream_t stream) {
    // Robust input binding: x has B*L*C*H*W = 50,331,648 elems; params has 2048.
    const void* x;
    const void* params;
    if (n_in >= 2 && in_sizes[0] == 2 * C * R) { params = d_in[0]; x = d_in[1]; }
    else                                        { x = d_in[0]; params = d_in[1]; }
    float* y = (float*)d_out;

    // Grid: x-dim = hw chunks (32768 / (256 threads * 2 elem) = 64), y-dim = B*C planes.
    dim3 grid(HW / 512, BB * C);
    convlru_kernel<<<grid, 256, 0, stream>>>(x, params, y);
}